// Round 2
// baseline (3184.583 us; speedup 1.0000x reference)
//
#include <hip/hip_runtime.h>

#define NN 50000
#define NE 1600000

using bf16x8 = __bf16 __attribute__((ext_vector_type(8)));
using bf16x4 = __bf16 __attribute__((ext_vector_type(4)));
using f32x4  = float  __attribute__((ext_vector_type(4)));

__device__ __forceinline__ char* swzp(void* base, int row, int byteoff) {
  return (char*)base + (byteoff ^ ((row & 7) << 4));
}
__device__ __forceinline__ const char* swzpc(const void* base, int row, int byteoff) {
  return (const char*)base + (byteoff ^ ((row & 7) << 4));
}

// edge_index may be int32 (JAX default, x64 disabled) or int64. Runtime-detected flag.
__device__ __forceinline__ int ld_idx(const void* p, int f64, long long i) {
  return f64 ? (int)((const long long*)p)[i] : ((const int*)p)[i];
}

__global__ void detect_idx64(const int* ei32, int* flag) {
  __shared__ int anynz;
  if (threadIdx.x == 0) anynz = 0;
  __syncthreads();
  if (ei32[2 * threadIdx.x + 1] != 0) atomicOr(&anynz, 1);
  __syncthreads();
  if (threadIdx.x == 0) *flag = (anynz == 0) ? 1 : 0;
}

// Convert weights to bf16 scratch copies.
__global__ void prep_weights(const float* We, const float* Whu, const float* Whw,
                             const float* W2, const float* Wemb, const float* Wattr,
                             __bf16* wHUW, __bf16* wET2, __bf16* wE, __bf16* wA) {
  int i = blockIdx.x * 256 + threadIdx.x;
  if (i < 65536) {
    int n = i >> 8, k = i & 255;
    wHUW[i] = (__bf16)(n < 128 ? Whu[n * 256 + k] : Whw[(n - 128) * 256 + k]);
  } else if (i < 131072) {
    int j = i - 65536; int n = j >> 8, k = j & 255;
    wET2[j] = (__bf16)(n < 128 ? Wemb[n * 256 + k] : W2[(n - 128) * 256 + k]);
  } else if (i < 147456) {
    int j = i - 131072; wE[j] = (__bf16)We[j];
  } else {
    int j = i - 147456; wA[j] = (__bf16)Wattr[j];
  }
}

__global__ void count_edges(const void* ei, const int* flag, float* cnt) {
  int i = blockIdx.x * 256 + threadIdx.x;
  int f = *flag;
  int t = ld_idx(ei, f, (long long)NE + i);
  unsafeAtomicAdd(&cnt[t], 1.0f);
}

// C[M,256] = A[M,256] @ W[256,256]^T  (A f32 -> bf16 on the fly, W bf16 pre-staged)
// MODE 0: store bf16 hu (cols 0-127) / hw (cols 128-255)
// MODE 1: out = acc[emb] + lrelu(acc[t2] + sums/max(cnt,1))
template <int MODE>
__global__ __launch_bounds__(512) void node_gemm(
    const float* __restrict__ x, const __bf16* __restrict__ W,
    __bf16* __restrict__ hu, __bf16* __restrict__ hw,
    const float* __restrict__ sums, const float* __restrict__ cnt,
    float* __restrict__ out) {
  __shared__ __bf16 sW[256 * 256];  // 128 KB, XOR-swizzled
  const int t = threadIdx.x;
  const int lane = t & 63;
  const int w = t >> 6;  // 0..7

  for (int i = t; i < 8192; i += 512) {
    int row = i >> 5, c8 = (i & 31) << 3;
    bf16x8 v = *(const bf16x8*)(W + row * 256 + c8);
    *(bf16x8*)swzp(sW, row, row * 512 + (c8 << 1)) = v;
  }
  __syncthreads();

  const int ntiles = (NN + 127) / 128;  // 391
  for (int tile = blockIdx.x; tile < ntiles; tile += gridDim.x) {
    int m0 = tile * 128 + w * 16;
    int arow = m0 + (lane & 15);
    f32x4 acc[16];
#pragma unroll
    for (int n = 0; n < 16; ++n) { acc[n][0] = 0.f; acc[n][1] = 0.f; acc[n][2] = 0.f; acc[n][3] = 0.f; }
#pragma unroll
    for (int ks = 0; ks < 8; ++ks) {
      bf16x8 a;
      if (arow < NN) {
        const float* ap = x + (long long)arow * 256 + ks * 32 + ((lane >> 4) << 3);
        f32x4 fa = *(const f32x4*)ap;
        f32x4 fb = *(const f32x4*)(ap + 4);
#pragma unroll
        for (int j = 0; j < 4; ++j) { a[j] = (__bf16)fa[j]; a[j + 4] = (__bf16)fb[j]; }
      } else {
#pragma unroll
        for (int j = 0; j < 8; ++j) a[j] = (__bf16)0.f;
      }
#pragma unroll
      for (int n = 0; n < 16; ++n) {
        int row = n * 16 + (lane & 15);
        bf16x8 b = *(const bf16x8*)swzpc(sW, row, row * 512 + ks * 64 + ((lane >> 4) << 4));
        acc[n] = __builtin_amdgcn_mfma_f32_16x16x32_bf16(a, b, acc[n], 0, 0, 0);
      }
    }
    const int NOUT = (MODE == 0) ? 16 : 8;
#pragma unroll
    for (int n = 0; n < NOUT; ++n) {
      int col = n * 16 + (lane & 15);
#pragma unroll
      for (int j = 0; j < 4; ++j) {
        int row = m0 + ((lane >> 4) << 2) + j;
        if (row < NN) {
          if (MODE == 0) {
            float v = acc[n][j];
            if (col < 128) hu[(long long)row * 128 + col] = (__bf16)v;
            else           hw[(long long)row * 128 + (col - 128)] = (__bf16)v;
          } else {
            float c = cnt[row];
            float agg = sums[(long long)row * 128 + col] / fmaxf(c, 1.0f);
            float z = acc[n + 8][j] + agg;
            float lr = z >= 0.f ? z : 0.01f * z;
            out[(long long)row * 128 + col] = acc[n][j] + lr;
          }
        }
      }
    }
  }
}

// Wave-independent fused edge pipeline (no __syncthreads in main loop).
// Swapped GEMM1: msg^T[col][edge] = We . eattr^T  -> lane owns edge (lane&15).
// hs add per-lane, atomic scatter, per-wave 4KB LDS transpose, GEMM2.
__global__ __launch_bounds__(256) void edge_fused(
    const float* __restrict__ eattr, const void* __restrict__ ei, const int* __restrict__ flag,
    const __bf16* __restrict__ wE, const __bf16* __restrict__ wA,
    const __bf16* __restrict__ hu, const __bf16* __restrict__ hw,
    float* __restrict__ sums, float* __restrict__ attr_out) {
  __shared__ __bf16 sW1[128 * 128];       // We, swizzled   (32 KB)
  __shared__ __bf16 sW2[128 * 128];       // Wattr, swizzled(32 KB)
  __shared__ __bf16 sMSG[4 * 16 * 128];   // per-wave msg^T (16 KB)

  const int t = threadIdx.x;
  const int lane = t & 63;
  const int w = t >> 6;       // 0..3
  const int h = lane >> 4;    // 0..3  (K-chunk group)
  const int l15 = lane & 15;  // edge-within-wave / row index
  const int f = *flag;
  __bf16* myMsgT = sMSG + w * 2048;  // 16 rows x 128 cols bf16 = 4 KB

  for (int i = t; i < 2048; i += 256) {
    int row = i >> 4, c8 = (i & 15) << 3;
    bf16x8 v1 = *(const bf16x8*)(wE + row * 128 + c8);
    bf16x8 v2 = *(const bf16x8*)(wA + row * 128 + c8);
    int b = row * 256 + (c8 << 1);
    *(bf16x8*)swzp(sW1, row, b) = v1;
    *(bf16x8*)swzp(sW2, row, b) = v2;
  }
  __syncthreads();  // the only block-wide barrier

  const int ntiles = NE / 64;  // 25000 ; each block-tile = 64 edges, wave w owns 16
  int tile = blockIdx.x;
  if (tile >= ntiles) return;

  // ---- prologue load (indices + eattr B-fragments) for first tile ----
  int srcI, tgtI;
  bf16x8 bfr[4];
  {
    int e = tile * 64 + w * 16 + l15;
    srcI = ld_idx(ei, f, e);
    tgtI = ld_idx(ei, f, (long long)NE + e);
    const float* ep = eattr + (long long)e * 128 + h * 8;
#pragma unroll
    for (int kc = 0; kc < 4; ++kc) {
      f32x4 fa = *(const f32x4*)(ep + kc * 32);
      f32x4 fb = *(const f32x4*)(ep + kc * 32 + 4);
#pragma unroll
      for (int j = 0; j < 4; ++j) { bfr[kc][j] = (__bf16)fa[j]; bfr[kc][j + 4] = (__bf16)fb[j]; }
    }
  }

  while (true) {
    // ---- issue hs gathers for current tile (hit L2/L3; land during GEMM1) ----
    bf16x4 hu4[8], hw4[8];
    {
      const __bf16* hup = hu + (long long)srcI * 128 + h * 4;
      const __bf16* hwp = hw + (long long)tgtI * 128 + h * 4;
#pragma unroll
      for (int n = 0; n < 8; ++n) {
        hu4[n] = *(const bf16x4*)(hup + n * 16);
        hw4[n] = *(const bf16x4*)(hwp + n * 16);
      }
    }
    const int tgtA = tgtI;
    const int eBase = tile * 64 + w * 16;

    // ---- GEMM1: acc[n] = msg^T tile, A=We from LDS, B=eattr frags ----
    f32x4 acc[8];
#pragma unroll
    for (int n = 0; n < 8; ++n) { acc[n][0] = 0.f; acc[n][1] = 0.f; acc[n][2] = 0.f; acc[n][3] = 0.f; }
#pragma unroll
    for (int kc = 0; kc < 4; ++kc) {
#pragma unroll
      for (int n = 0; n < 8; ++n) {
        int row = n * 16 + l15;
        bf16x8 a = *(const bf16x8*)swzpc(sW1, row, row * 256 + kc * 64 + h * 16);
        acc[n] = __builtin_amdgcn_mfma_f32_16x16x32_bf16(a, bfr[kc], acc[n], 0, 0, 0);
      }
    }

    // ---- prefetch next tile (indices + eattr) while epilogue/GEMM2 run ----
    int ntile = tile + gridDim.x;
    if (ntile < ntiles) {
      int e = ntile * 64 + w * 16 + l15;
      srcI = ld_idx(ei, f, e);
      tgtI = ld_idx(ei, f, (long long)NE + e);
      const float* ep = eattr + (long long)e * 128 + h * 8;
#pragma unroll
      for (int kc = 0; kc < 4; ++kc) {
        f32x4 fa = *(const f32x4*)(ep + kc * 32);
        f32x4 fb = *(const f32x4*)(ep + kc * 32 + 4);
#pragma unroll
        for (int j = 0; j < 4; ++j) { bfr[kc][j] = (__bf16)fa[j]; bfr[kc][j + 4] = (__bf16)fb[j]; }
      }
    }

    // ---- epilogue 1: + hu[src] + hw[tgt], lrelu, atomic scatter, msgT write ----
    // lane's data: msg[edge = eBase + l15][col = n*16 + h*4 + j]
#pragma unroll
    for (int n = 0; n < 8; ++n) {
      bf16x4 mv;
#pragma unroll
      for (int j = 0; j < 4; ++j) {
        float z = acc[n][j] + (float)hu4[n][j] + (float)hw4[n][j];
        float m = z >= 0.f ? z : 0.01f * z;
        unsafeAtomicAdd(&sums[(long long)tgtA * 128 + n * 16 + h * 4 + j], m);
        mv[j] = (__bf16)m;
      }
      *(bf16x4*)swzp(myMsgT, l15, l15 * 256 + n * 32 + h * 8) = mv;
    }

    // ---- GEMM2: attr[edge][:] = msg @ Wattr^T ; A=msgT from LDS, B=Wattr ----
    f32x4 acc2[8];
#pragma unroll
    for (int n = 0; n < 8; ++n) { acc2[n][0] = 0.f; acc2[n][1] = 0.f; acc2[n][2] = 0.f; acc2[n][3] = 0.f; }
#pragma unroll
    for (int kc = 0; kc < 4; ++kc) {
      bf16x8 a2 = *(const bf16x8*)swzpc(myMsgT, l15, l15 * 256 + kc * 64 + h * 16);
#pragma unroll
      for (int nt = 0; nt < 8; ++nt) {
        int row = nt * 16 + l15;
        bf16x8 b2 = *(const bf16x8*)swzpc(sW2, row, row * 256 + kc * 64 + h * 16);
        acc2[nt] = __builtin_amdgcn_mfma_f32_16x16x32_bf16(a2, b2, acc2[nt], 0, 0, 0);
      }
    }

    // ---- store attributes: row = eBase + h*4 + j, col = nt*16 + l15 ----
    float* op = attr_out + (long long)(eBase + h * 4) * 128 + l15;
#pragma unroll
    for (int nt = 0; nt < 8; ++nt) {
#pragma unroll
      for (int j = 0; j < 4; ++j) {
        op[j * 128 + nt * 16] = acc2[nt][j];
      }
    }

    if (ntile >= ntiles) break;
    tile = ntile;
  }
}

extern "C" void kernel_launch(void* const* d_in, const int* in_sizes, int n_in,
                              void* d_out, int out_size, void* d_ws, size_t ws_size,
                              hipStream_t stream) {
  const float* x     = (const float*)d_in[0];
  const void*  ei    = d_in[1];
  const float* eattr = (const float*)d_in[2];
  const float* We    = (const float*)d_in[3];
  const float* Whu   = (const float*)d_in[4];
  const float* Whw   = (const float*)d_in[5];
  const float* W2    = (const float*)d_in[6];
  const float* Wemb  = (const float*)d_in[7];
  const float* Wattr = (const float*)d_in[8];

  float* out_emb  = (float*)d_out;
  float* out_attr = out_emb + (size_t)NN * 128;

  char* ws = (char*)d_ws;
  float*  sums = (float*)ws;                          // 25,600,000 B
  float*  cnt  = (float*)(ws + 25600000);             //    200,000 B
  int*    flag = (int*)(ws + 25800000);
  __bf16* hu   = (__bf16*)(ws + 25800064);            // 12,800,000 B
  __bf16* hw   = (__bf16*)(ws + 25800064 + 12800000); // 12,800,000 B
  __bf16* wHUW = (__bf16*)(ws + 25800064 + 25600000); //    131,072 B
  __bf16* wET2 = wHUW + 65536;
  __bf16* wE   = wET2 + 65536;
  __bf16* wA   = wE + 16384;

  hipMemsetAsync(sums, 0, 25800000, stream);  // sums + cnt
  detect_idx64<<<1, 1024, 0, stream>>>((const int*)ei, flag);
  prep_weights<<<640, 256, 0, stream>>>(We, Whu, Whw, W2, Wemb, Wattr, wHUW, wET2, wE, wA);
  count_edges<<<6250, 256, 0, stream>>>(ei, flag, cnt);
  node_gemm<0><<<391, 512, 0, stream>>>(x, wHUW, hu, hw, nullptr, nullptr, nullptr);
  edge_fused<<<512, 256, 0, stream>>>(eattr, ei, flag, wE, wA, hu, hw, sums, out_attr);
  node_gemm<1><<<391, 512, 0, stream>>>(x, wET2, nullptr, nullptr, sums, cnt, out_emb);
}

// Round 3
// 1294.920 us; speedup vs baseline: 2.4593x; 2.4593x over previous
//
#include <hip/hip_runtime.h>

#define NN 50000
#define NE 1600000

using bf16x8 = __bf16 __attribute__((ext_vector_type(8)));
using f32x4  = float  __attribute__((ext_vector_type(4)));

__device__ __forceinline__ char* swzp(void* base, int row, int byteoff) {
  return (char*)base + (byteoff ^ ((row & 7) << 4));
}
__device__ __forceinline__ const char* swzpc(const void* base, int row, int byteoff) {
  return (const char*)base + (byteoff ^ ((row & 7) << 4));
}

// edge_index may be int32 (JAX default, x64 disabled) or int64. Runtime-detected flag.
__device__ __forceinline__ int ld_idx(const void* p, int f64, long long i) {
  return f64 ? (int)((const long long*)p)[i] : ((const int*)p)[i];
}

__global__ void detect_idx64(const int* ei32, int* flag) {
  __shared__ int anynz;
  if (threadIdx.x == 0) anynz = 0;
  __syncthreads();
  if (ei32[2 * threadIdx.x + 1] != 0) atomicOr(&anynz, 1);
  __syncthreads();
  if (threadIdx.x == 0) *flag = (anynz == 0) ? 1 : 0;
}

__global__ void prep_weights(const float* We, const float* Whu, const float* Whw,
                             const float* W2, const float* Wemb, const float* Wattr,
                             __bf16* wHUW, __bf16* wET2, __bf16* wE, __bf16* wA) {
  int i = blockIdx.x * 256 + threadIdx.x;
  if (i < 65536) {
    int n = i >> 8, k = i & 255;
    wHUW[i] = (__bf16)(n < 128 ? Whu[n * 256 + k] : Whw[(n - 128) * 256 + k]);
  } else if (i < 131072) {
    int j = i - 65536; int n = j >> 8, k = j & 255;
    wET2[j] = (__bf16)(n < 128 ? Wemb[n * 256 + k] : W2[(n - 128) * 256 + k]);
  } else if (i < 147456) {
    int j = i - 131072; wE[j] = (__bf16)We[j];
  } else {
    int j = i - 147456; wA[j] = (__bf16)Wattr[j];
  }
}

// ---- counting sort of edges by tgt ----
__global__ void k_hist(const void* ei, const int* flag, int* cnt) {
  int i = blockIdx.x * 256 + threadIdx.x;
  int t = ld_idx(ei, *flag, (long long)NE + i);
  atomicAdd(&cnt[t], 1);
}

__global__ void k_part(const int* cnt, int* part) {
  __shared__ int red[256];
  int i = blockIdx.x * 256 + threadIdx.x;
  red[threadIdx.x] = (i < NN) ? cnt[i] : 0;
  __syncthreads();
  for (int s = 128; s > 0; s >>= 1) {
    if (threadIdx.x < s) red[threadIdx.x] += red[threadIdx.x + s];
    __syncthreads();
  }
  if (threadIdx.x == 0) part[blockIdx.x] = red[0];
}

__global__ void k_scanpart(int* part, int n) {
  if (threadIdx.x == 0) {
    int acc = 0;
    for (int i = 0; i < n; ++i) { int v = part[i]; part[i] = acc; acc += v; }
  }
}

__global__ void k_offsets(const int* cnt, const int* part, int* offs) {
  __shared__ int sc[256];
  int i = blockIdx.x * 256 + threadIdx.x;
  int v = (i < NN) ? cnt[i] : 0;
  sc[threadIdx.x] = v;
  __syncthreads();
  for (int d = 1; d < 256; d <<= 1) {
    int add = (threadIdx.x >= d) ? sc[threadIdx.x - d] : 0;
    __syncthreads();
    sc[threadIdx.x] += add;
    __syncthreads();
  }
  if (i < NN) offs[i] = part[blockIdx.x] + sc[threadIdx.x] - v;  // exclusive
}

__global__ void k_scatter(const void* ei, const int* flag, const int* offs,
                          int* fill, int* perm) {
  int i = blockIdx.x * 256 + threadIdx.x;
  int t = ld_idx(ei, *flag, (long long)NE + i);
  int pos = offs[t] + atomicAdd(&fill[t], 1);
  perm[pos] = i;
}

// C[M,256] = A[M,256] @ W[256,256]^T  (A f32 -> bf16 on the fly, W bf16 pre-staged)
// MODE 0: store bf16 hu (cols 0-127) / hw (cols 128-255)
// MODE 1: out = acc[emb] + lrelu(acc[t2] + sums/max(cnt,1))
template <int MODE>
__global__ __launch_bounds__(512) void node_gemm(
    const float* __restrict__ x, const __bf16* __restrict__ W,
    __bf16* __restrict__ hu, __bf16* __restrict__ hw,
    const float* __restrict__ sums, const int* __restrict__ cnt,
    float* __restrict__ out) {
  __shared__ __bf16 sW[256 * 256];  // 128 KB, XOR-swizzled
  const int t = threadIdx.x;
  const int lane = t & 63;
  const int w = t >> 6;  // 0..7

  for (int i = t; i < 8192; i += 512) {
    int row = i >> 5, c8 = (i & 31) << 3;
    bf16x8 v = *(const bf16x8*)(W + row * 256 + c8);
    *(bf16x8*)swzp(sW, row, row * 512 + (c8 << 1)) = v;
  }
  __syncthreads();

  const int ntiles = (NN + 127) / 128;  // 391
  for (int tile = blockIdx.x; tile < ntiles; tile += gridDim.x) {
    int m0 = tile * 128 + w * 16;
    int arow = m0 + (lane & 15);
    f32x4 acc[16];
#pragma unroll
    for (int n = 0; n < 16; ++n) { acc[n][0] = 0.f; acc[n][1] = 0.f; acc[n][2] = 0.f; acc[n][3] = 0.f; }
#pragma unroll
    for (int ks = 0; ks < 8; ++ks) {
      bf16x8 a;
      if (arow < NN) {
        const float* ap = x + (long long)arow * 256 + ks * 32 + ((lane >> 4) << 3);
        f32x4 fa = *(const f32x4*)ap;
        f32x4 fb = *(const f32x4*)(ap + 4);
#pragma unroll
        for (int j = 0; j < 4; ++j) { a[j] = (__bf16)fa[j]; a[j + 4] = (__bf16)fb[j]; }
      } else {
#pragma unroll
        for (int j = 0; j < 8; ++j) a[j] = (__bf16)0.f;
      }
#pragma unroll
      for (int n = 0; n < 16; ++n) {
        int row = n * 16 + (lane & 15);
        bf16x8 b = *(const bf16x8*)swzpc(sW, row, row * 512 + ks * 64 + ((lane >> 4) << 4));
        acc[n] = __builtin_amdgcn_mfma_f32_16x16x32_bf16(a, b, acc[n], 0, 0, 0);
      }
    }
    const int NOUT = (MODE == 0) ? 16 : 8;
#pragma unroll
    for (int n = 0; n < NOUT; ++n) {
      int col = n * 16 + (lane & 15);
#pragma unroll
      for (int j = 0; j < 4; ++j) {
        int row = m0 + ((lane >> 4) << 2) + j;
        if (row < NN) {
          if (MODE == 0) {
            float v = acc[n][j];
            if (col < 128) hu[(long long)row * 128 + col] = (__bf16)v;
            else           hw[(long long)row * 128 + (col - 128)] = (__bf16)v;
          } else {
            float c = (float)cnt[row];
            float agg = sums[(long long)row * 128 + col] / fmaxf(c, 1.0f);
            float z = acc[n + 8][j] + agg;
            float lr = z >= 0.f ? z : 0.01f * z;
            out[(long long)row * 128 + col] = acc[n][j] + lr;
          }
        }
      }
    }
  }
}

// Fused edge pipeline over TGT-SORTED edge permutation.
// msg = lrelu(eattr[perm]@We^T + hu[src]+hw[tgt]); segment-reduce msg by tgt
// (contiguous runs) into sums; attributes[perm] = msg@Wattr^T.
__global__ __launch_bounds__(512) void edge_fused(
    const float* __restrict__ eattr, const void* __restrict__ ei,
    const int* __restrict__ flag, const int* __restrict__ perm,
    const __bf16* __restrict__ wE, const __bf16* __restrict__ wA,
    const __bf16* __restrict__ hu, const __bf16* __restrict__ hw,
    float* __restrict__ sums, float* __restrict__ attr_out) {
  __shared__ __bf16 sW1[128 * 128];  // We, swizzled (32 KB)
  __shared__ __bf16 sW2[128 * 128];  // Wattr, swizzled (32 KB)
  __shared__ __bf16 sM[128 * 128];   // hs -> msg in-place, swizzled (32 KB)
  __shared__ int sPerm[128], sSrc[128], sTgt[128];

  const int t = threadIdx.x;
  const int lane = t & 63;
  const int w = t >> 6;       // 0..7
  const int h = lane >> 4;    // 0..3
  const int l15 = lane & 15;
  const int f = *flag;

  for (int i = t; i < 2048; i += 512) {
    int row = i >> 4, c8 = (i & 15) << 3;
    bf16x8 v1 = *(const bf16x8*)(wE + row * 128 + c8);
    bf16x8 v2 = *(const bf16x8*)(wA + row * 128 + c8);
    int b = row * 256 + (c8 << 1);
    *(bf16x8*)swzp(sW1, row, b) = v1;
    *(bf16x8*)swzp(sW2, row, b) = v2;
  }

  const int ntiles = NE / 128;  // 12500
  for (int tile = blockIdx.x; tile < ntiles; tile += gridDim.x) {
    __syncthreads();  // protect sM/sPerm/etc from previous iteration readers
    int e0 = tile * 128;
    if (t < 128) {
      int p = perm[e0 + t];
      sPerm[t] = p;
      sSrc[t] = ld_idx(ei, f, p);
      sTgt[t] = ld_idx(ei, f, (long long)NE + p);
    }
    __syncthreads();

    // gather hs = hu[src] + hw[tgt] into sM (swizzled)
    for (int i = t; i < 2048; i += 512) {
      int r = i >> 4, c8 = (i & 15) << 3;
      bf16x8 a = *(const bf16x8*)(hu + (long long)sSrc[r] * 128 + c8);
      bf16x8 b = *(const bf16x8*)(hw + (long long)sTgt[r] * 128 + c8);
      bf16x8 o;
#pragma unroll
      for (int j = 0; j < 8; ++j) o[j] = (__bf16)((float)a[j] + (float)b[j]);
      *(bf16x8*)swzp(sM, r, r * 256 + (c8 << 1)) = o;
    }
    __syncthreads();

    // GEMM1: wave w owns local edges w*16..w*16+15 (rows of A = eattr[perm])
    const int myE = sPerm[w * 16 + l15];
    const float* Abase = eattr + (long long)myE * 128;
    f32x4 acc[8];
#pragma unroll
    for (int n = 0; n < 8; ++n) { acc[n][0] = 0.f; acc[n][1] = 0.f; acc[n][2] = 0.f; acc[n][3] = 0.f; }
#pragma unroll
    for (int ks = 0; ks < 4; ++ks) {
      f32x4 fa = *(const f32x4*)(Abase + ks * 32 + (h << 3));
      f32x4 fb = *(const f32x4*)(Abase + ks * 32 + (h << 3) + 4);
      bf16x8 a;
#pragma unroll
      for (int j = 0; j < 4; ++j) { a[j] = (__bf16)fa[j]; a[j + 4] = (__bf16)fb[j]; }
#pragma unroll
      for (int n = 0; n < 8; ++n) {
        int row = n * 16 + l15;
        bf16x8 b = *(const bf16x8*)swzpc(sW1, row, row * 256 + ks * 64 + (h << 4));
        acc[n] = __builtin_amdgcn_mfma_f32_16x16x32_bf16(a, b, acc[n], 0, 0, 0);
      }
    }

    // epilogue 1: msg = lrelu(acc + hs), written back in place (same lane RMW)
#pragma unroll
    for (int n = 0; n < 8; ++n) {
      int col = n * 16 + l15;
#pragma unroll
      for (int j = 0; j < 4; ++j) {
        int rl = w * 16 + (h << 2) + j;
        __bf16* mp = (__bf16*)swzp(sM, rl, rl * 256 + (col << 1));
        float z = acc[n][j] + (float)*mp;
        float m = z >= 0.f ? z : 0.01f * z;
        *mp = (__bf16)m;
      }
    }
    __syncthreads();

    // segment reduce by tgt (sorted -> contiguous runs), coalesced atomics
    {
      int c = t & 127, q = t >> 7;  // q uniform per wave
      float s = 0.f;
      int cur = sTgt[q * 32];
#pragma unroll 4
      for (int r = q * 32; r < q * 32 + 32; ++r) {
        int tg = sTgt[r];
        if (tg != cur) {
          unsafeAtomicAdd(&sums[(long long)cur * 128 + c], s);
          s = 0.f; cur = tg;
        }
        s += (float)*(const __bf16*)swzpc(sM, r, r * 256 + (c << 1));
      }
      unsafeAtomicAdd(&sums[(long long)cur * 128 + c], s);
    }

    // GEMM2: attributes = msg @ Wattr^T (A = own-wave msg rows from sM)
    f32x4 acc2[8];
#pragma unroll
    for (int n = 0; n < 8; ++n) { acc2[n][0] = 0.f; acc2[n][1] = 0.f; acc2[n][2] = 0.f; acc2[n][3] = 0.f; }
    int rA = w * 16 + l15;
#pragma unroll
    for (int ks = 0; ks < 4; ++ks) {
      bf16x8 a2 = *(const bf16x8*)swzpc(sM, rA, rA * 256 + ks * 64 + (h << 4));
#pragma unroll
      for (int nt = 0; nt < 8; ++nt) {
        int row = nt * 16 + l15;
        bf16x8 b2 = *(const bf16x8*)swzpc(sW2, row, row * 256 + ks * 64 + (h << 4));
        acc2[nt] = __builtin_amdgcn_mfma_f32_16x16x32_bf16(a2, b2, acc2[nt], 0, 0, 0);
      }
    }
    int gr[4];
#pragma unroll
    for (int j = 0; j < 4; ++j) gr[j] = sPerm[w * 16 + (h << 2) + j];
#pragma unroll
    for (int nt = 0; nt < 8; ++nt) {
#pragma unroll
      for (int j = 0; j < 4; ++j) {
        attr_out[(long long)gr[j] * 128 + nt * 16 + l15] = acc2[nt][j];
      }
    }
  }
}

extern "C" void kernel_launch(void* const* d_in, const int* in_sizes, int n_in,
                              void* d_out, int out_size, void* d_ws, size_t ws_size,
                              hipStream_t stream) {
  const float* x     = (const float*)d_in[0];
  const void*  ei    = d_in[1];
  const float* eattr = (const float*)d_in[2];
  const float* We    = (const float*)d_in[3];
  const float* Whu   = (const float*)d_in[4];
  const float* Whw   = (const float*)d_in[5];
  const float* W2    = (const float*)d_in[6];
  const float* Wemb  = (const float*)d_in[7];
  const float* Wattr = (const float*)d_in[8];

  float* out_emb  = (float*)d_out;
  float* out_attr = out_emb + (size_t)NN * 128;

  char* ws = (char*)d_ws;
  float*  sums = (float*)ws;                       // 25,600,000
  int*    cnt  = (int*)(ws + 25600000);            //    200,064
  int*    fill = (int*)(ws + 25800064);            //    200,064
  int*    offs = (int*)(ws + 26000128);            //    200,064
  int*    part = (int*)(ws + 26200192);            //      1,024
  int*    flag = (int*)(ws + 26201216);            //         64
  int*    perm = (int*)(ws + 26201280);            //  6,400,000
  __bf16* hu   = (__bf16*)(ws + 32601280);         // 12,800,000
  __bf16* hw   = (__bf16*)(ws + 45401280);         // 12,800,000
  __bf16* wHUW = (__bf16*)(ws + 58201280);         //    131,072
  __bf16* wET2 = wHUW + 65536;
  __bf16* wE   = wET2 + 65536;
  __bf16* wA   = wE + 16384;

  hipMemsetAsync(ws, 0, 26000128, stream);  // sums + cnt + fill
  detect_idx64<<<1, 1024, 0, stream>>>((const int*)ei, flag);
  prep_weights<<<640, 256, 0, stream>>>(We, Whu, Whw, W2, Wemb, Wattr, wHUW, wET2, wE, wA);
  k_hist<<<6250, 256, 0, stream>>>(ei, flag, cnt);
  k_part<<<196, 256, 0, stream>>>(cnt, part);
  k_scanpart<<<1, 64, 0, stream>>>(part, 196);
  k_offsets<<<196, 256, 0, stream>>>(cnt, part, offs);
  k_scatter<<<6250, 256, 0, stream>>>(ei, flag, offs, fill, perm);
  node_gemm<0><<<391, 512, 0, stream>>>(x, wHUW, hu, hw, nullptr, nullptr, nullptr);
  edge_fused<<<512, 512, 0, stream>>>(eattr, ei, flag, perm, wE, wA, hu, hw, sums, out_attr);
  node_gemm<1><<<391, 512, 0, stream>>>(x, wET2, nullptr, nullptr, sums, cnt, out_emb);
}

// Round 4
// 1221.864 us; speedup vs baseline: 2.6063x; 1.0598x over previous
//
#include <hip/hip_runtime.h>

#define NN 50000
#define NE 1600000

using bf16x8 = __bf16 __attribute__((ext_vector_type(8)));
using f32x4  = float  __attribute__((ext_vector_type(4)));

__device__ __forceinline__ char* swzp(void* base, int row, int byteoff) {
  return (char*)base + (byteoff ^ ((row & 7) << 4));
}
__device__ __forceinline__ const char* swzpc(const void* base, int row, int byteoff) {
  return (const char*)base + (byteoff ^ ((row & 7) << 4));
}

// edge_index may be int32 (JAX default, x64 disabled) or int64. Runtime-detected flag.
__device__ __forceinline__ int ld_idx(const void* p, int f64, long long i) {
  return f64 ? (int)((const long long*)p)[i] : ((const int*)p)[i];
}

__global__ void detect_idx64(const int* ei32, int* flag) {
  __shared__ int anynz;
  if (threadIdx.x == 0) anynz = 0;
  __syncthreads();
  if (ei32[2 * threadIdx.x + 1] != 0) atomicOr(&anynz, 1);
  __syncthreads();
  if (threadIdx.x == 0) *flag = (anynz == 0) ? 1 : 0;
}

__global__ void prep_weights(const float* We, const float* Whu, const float* Whw,
                             const float* W2, const float* Wemb, const float* Wattr,
                             __bf16* wHUW, __bf16* wET2, __bf16* wE, __bf16* wA) {
  int i = blockIdx.x * 256 + threadIdx.x;
  if (i < 65536) {
    int n = i >> 8, k = i & 255;
    wHUW[i] = (__bf16)(n < 128 ? Whu[n * 256 + k] : Whw[(n - 128) * 256 + k]);
  } else if (i < 131072) {
    int j = i - 65536; int n = j >> 8, k = j & 255;
    wET2[j] = (__bf16)(n < 128 ? Wemb[n * 256 + k] : W2[(n - 128) * 256 + k]);
  } else if (i < 147456) {
    int j = i - 131072; wE[j] = (__bf16)We[j];
  } else {
    int j = i - 147456; wA[j] = (__bf16)Wattr[j];
  }
}

// ---- counting sort of edges by tgt ----
__global__ void k_hist(const void* ei, const int* flag, int* cnt) {
  int i = blockIdx.x * 256 + threadIdx.x;
  int t = ld_idx(ei, *flag, (long long)NE + i);
  atomicAdd(&cnt[t], 1);
}

__global__ void k_part(const int* cnt, int* part) {
  __shared__ int red[256];
  int i = blockIdx.x * 256 + threadIdx.x;
  red[threadIdx.x] = (i < NN) ? cnt[i] : 0;
  __syncthreads();
  for (int s = 128; s > 0; s >>= 1) {
    if (threadIdx.x < s) red[threadIdx.x] += red[threadIdx.x + s];
    __syncthreads();
  }
  if (threadIdx.x == 0) part[blockIdx.x] = red[0];
}

// one-block parallel exclusive scan over n<=256 partials
__global__ void k_scanpart(int* part, int n) {
  __shared__ int sc[256];
  int v = (threadIdx.x < n) ? part[threadIdx.x] : 0;
  sc[threadIdx.x] = v;
  __syncthreads();
  for (int d = 1; d < 256; d <<= 1) {
    int add = (threadIdx.x >= d) ? sc[threadIdx.x - d] : 0;
    __syncthreads();
    sc[threadIdx.x] += add;
    __syncthreads();
  }
  if (threadIdx.x < n) part[threadIdx.x] = sc[threadIdx.x] - v;  // exclusive
}

__global__ void k_offsets(const int* cnt, const int* part, int* offs) {
  __shared__ int sc[256];
  int i = blockIdx.x * 256 + threadIdx.x;
  int v = (i < NN) ? cnt[i] : 0;
  sc[threadIdx.x] = v;
  __syncthreads();
  for (int d = 1; d < 256; d <<= 1) {
    int add = (threadIdx.x >= d) ? sc[threadIdx.x - d] : 0;
    __syncthreads();
    sc[threadIdx.x] += add;
    __syncthreads();
  }
  if (i < NN) offs[i] = part[blockIdx.x] + sc[threadIdx.x] - v;  // exclusive
}

__global__ void k_scatter(const void* ei, const int* flag, const int* offs,
                          int* fill, int* perm) {
  int i = blockIdx.x * 256 + threadIdx.x;
  int t = ld_idx(ei, *flag, (long long)NE + i);
  int pos = offs[t] + atomicAdd(&fill[t], 1);
  perm[pos] = i;
}

// C[M,256] = A[M,256] @ W[256,256]^T  (A f32 -> bf16 on the fly, W bf16 pre-staged)
// MODE 0: store bf16 hu (cols 0-127) / hw (cols 128-255)
// MODE 1: out = acc[emb] + lrelu(acc[t2] + sums/max(cnt,1))
template <int MODE>
__global__ __launch_bounds__(512) void node_gemm(
    const float* __restrict__ x, const __bf16* __restrict__ W,
    __bf16* __restrict__ hu, __bf16* __restrict__ hw,
    const float* __restrict__ sums, const int* __restrict__ cnt,
    float* __restrict__ out) {
  __shared__ __bf16 sW[256 * 256];  // 128 KB, XOR-swizzled
  const int t = threadIdx.x;
  const int lane = t & 63;
  const int w = t >> 6;  // 0..7

  for (int i = t; i < 8192; i += 512) {
    int row = i >> 5, c8 = (i & 31) << 3;
    bf16x8 v = *(const bf16x8*)(W + row * 256 + c8);
    *(bf16x8*)swzp(sW, row, row * 512 + (c8 << 1)) = v;
  }
  __syncthreads();

  const int ntiles = (NN + 127) / 128;  // 391
  for (int tile = blockIdx.x; tile < ntiles; tile += gridDim.x) {
    int m0 = tile * 128 + w * 16;
    int arow = m0 + (lane & 15);
    f32x4 acc[16];
#pragma unroll
    for (int n = 0; n < 16; ++n) { acc[n][0] = 0.f; acc[n][1] = 0.f; acc[n][2] = 0.f; acc[n][3] = 0.f; }
#pragma unroll
    for (int ks = 0; ks < 8; ++ks) {
      bf16x8 a;
      if (arow < NN) {
        const float* ap = x + (long long)arow * 256 + ks * 32 + ((lane >> 4) << 3);
        f32x4 fa = *(const f32x4*)ap;
        f32x4 fb = *(const f32x4*)(ap + 4);
#pragma unroll
        for (int j = 0; j < 4; ++j) { a[j] = (__bf16)fa[j]; a[j + 4] = (__bf16)fb[j]; }
      } else {
#pragma unroll
        for (int j = 0; j < 8; ++j) a[j] = (__bf16)0.f;
      }
#pragma unroll
      for (int n = 0; n < 16; ++n) {
        int row = n * 16 + (lane & 15);
        bf16x8 b = *(const bf16x8*)swzpc(sW, row, row * 512 + ks * 64 + ((lane >> 4) << 4));
        acc[n] = __builtin_amdgcn_mfma_f32_16x16x32_bf16(a, b, acc[n], 0, 0, 0);
      }
    }
    const int NOUT = (MODE == 0) ? 16 : 8;
#pragma unroll
    for (int n = 0; n < NOUT; ++n) {
      int col = n * 16 + (lane & 15);
#pragma unroll
      for (int j = 0; j < 4; ++j) {
        int row = m0 + ((lane >> 4) << 2) + j;
        if (row < NN) {
          if (MODE == 0) {
            float v = acc[n][j];
            if (col < 128) hu[(long long)row * 128 + col] = (__bf16)v;
            else           hw[(long long)row * 128 + (col - 128)] = (__bf16)v;
          } else {
            float c = (float)cnt[row];
            float agg = sums[(long long)row * 128 + col] / fmaxf(c, 1.0f);
            float z = acc[n + 8][j] + agg;
            float lr = z >= 0.f ? z : 0.01f * z;
            out[(long long)row * 128 + col] = acc[n][j] + lr;
          }
        }
      }
    }
  }
}

// Fused edge pipeline over TGT-SORTED edge permutation, 1024 threads / 256-edge tiles.
// msg = lrelu(eattr[perm]@We^T + hu[src]+hw[tgt]); segment-reduce msg by tgt
// (contiguous runs) into sums; attributes[perm] = msg@Wattr^T.
__global__ __launch_bounds__(1024) void edge_fused(
    const float* __restrict__ eattr, const void* __restrict__ ei,
    const int* __restrict__ flag, const int* __restrict__ perm,
    const __bf16* __restrict__ wE, const __bf16* __restrict__ wA,
    const __bf16* __restrict__ hu, const __bf16* __restrict__ hw,
    float* __restrict__ sums, float* __restrict__ attr_out) {
  __shared__ __bf16 sW1[128 * 128];  // We, swizzled (32 KB)
  __shared__ __bf16 sW2[128 * 128];  // Wattr, swizzled (32 KB)
  __shared__ __bf16 sM[256 * 128];   // hs -> msg in-place, swizzled (64 KB)
  __shared__ int sPerm[256], sSrc[256], sTgt[256];

  const int t = threadIdx.x;
  const int lane = t & 63;
  const int w = t >> 6;       // 0..15
  const int h = lane >> 4;    // 0..3
  const int l15 = lane & 15;
  const int f = *flag;

  for (int i = t; i < 2048; i += 1024) {
    int row = i >> 4, c8 = (i & 15) << 3;
    bf16x8 v1 = *(const bf16x8*)(wE + row * 128 + c8);
    bf16x8 v2 = *(const bf16x8*)(wA + row * 128 + c8);
    int b = row * 256 + (c8 << 1);
    *(bf16x8*)swzp(sW1, row, b) = v1;
    *(bf16x8*)swzp(sW2, row, b) = v2;
  }

  const int ntiles = NE / 256;  // 6250
  for (int tile = blockIdx.x; tile < ntiles; tile += gridDim.x) {
    __syncthreads();  // protect sM/sPerm/etc from previous iteration readers
    int e0 = tile * 256;
    if (t < 256) {
      int p = perm[e0 + t];
      sPerm[t] = p;
      sSrc[t] = ld_idx(ei, f, p);
      sTgt[t] = ld_idx(ei, f, (long long)NE + p);
    }
    __syncthreads();

    // issue this wave's eattr A-loads first; their latency hides under the gather
    const int myE = sPerm[w * 16 + l15];
    const float* Abase = eattr + (long long)myE * 128;
    f32x4 fa[4], fb[4];
#pragma unroll
    for (int ks = 0; ks < 4; ++ks) {
      fa[ks] = *(const f32x4*)(Abase + ks * 32 + (h << 3));
      fb[ks] = *(const f32x4*)(Abase + ks * 32 + (h << 3) + 4);
    }

    // gather hs = hu[src] + hw[tgt] into sM (swizzled)
    for (int i = t; i < 4096; i += 1024) {
      int r = i >> 4, c8 = (i & 15) << 3;
      bf16x8 a = *(const bf16x8*)(hu + (long long)sSrc[r] * 128 + c8);
      bf16x8 b = *(const bf16x8*)(hw + (long long)sTgt[r] * 128 + c8);
      bf16x8 o;
#pragma unroll
      for (int j = 0; j < 8; ++j) o[j] = (__bf16)((float)a[j] + (float)b[j]);
      *(bf16x8*)swzp(sM, r, r * 256 + (c8 << 1)) = o;
    }
    __syncthreads();

    // GEMM1: wave w owns local edges w*16..w*16+15 (rows of A = eattr[perm])
    f32x4 acc[8];
#pragma unroll
    for (int n = 0; n < 8; ++n) { acc[n][0] = 0.f; acc[n][1] = 0.f; acc[n][2] = 0.f; acc[n][3] = 0.f; }
#pragma unroll
    for (int ks = 0; ks < 4; ++ks) {
      bf16x8 a;
#pragma unroll
      for (int j = 0; j < 4; ++j) { a[j] = (__bf16)fa[ks][j]; a[j + 4] = (__bf16)fb[ks][j]; }
#pragma unroll
      for (int n = 0; n < 8; ++n) {
        int row = n * 16 + l15;
        bf16x8 b = *(const bf16x8*)swzpc(sW1, row, row * 256 + ks * 64 + (h << 4));
        acc[n] = __builtin_amdgcn_mfma_f32_16x16x32_bf16(a, b, acc[n], 0, 0, 0);
      }
    }

    // epilogue 1: msg = lrelu(acc + hs), written back in place (same lane RMW)
#pragma unroll
    for (int n = 0; n < 8; ++n) {
      int col = n * 16 + l15;
#pragma unroll
      for (int j = 0; j < 4; ++j) {
        int rl = w * 16 + (h << 2) + j;
        __bf16* mp = (__bf16*)swzp(sM, rl, rl * 256 + (col << 1));
        float z = acc[n][j] + (float)*mp;
        float m = z >= 0.f ? z : 0.01f * z;
        *mp = (__bf16)m;
      }
    }
    __syncthreads();

    // segment reduce by tgt (sorted -> contiguous runs), coalesced atomics
    {
      int c = t & 127, q = t >> 7;  // q = 0..7, uniform per wave-pair
      float s = 0.f;
      int cur = sTgt[q * 32];
#pragma unroll 4
      for (int r = q * 32; r < q * 32 + 32; ++r) {
        int tg = sTgt[r];
        if (tg != cur) {
          unsafeAtomicAdd(&sums[(long long)cur * 128 + c], s);
          s = 0.f; cur = tg;
        }
        s += (float)*(const __bf16*)swzpc(sM, r, r * 256 + (c << 1));
      }
      unsafeAtomicAdd(&sums[(long long)cur * 128 + c], s);
    }

    // GEMM2: attributes = msg @ Wattr^T (A = own-wave msg rows from sM)
    f32x4 acc2[8];
#pragma unroll
    for (int n = 0; n < 8; ++n) { acc2[n][0] = 0.f; acc2[n][1] = 0.f; acc2[n][2] = 0.f; acc2[n][3] = 0.f; }
    int rA = w * 16 + l15;
#pragma unroll
    for (int ks = 0; ks < 4; ++ks) {
      bf16x8 a2 = *(const bf16x8*)swzpc(sM, rA, rA * 256 + ks * 64 + (h << 4));
#pragma unroll
      for (int nt = 0; nt < 8; ++nt) {
        int row = nt * 16 + l15;
        bf16x8 b2 = *(const bf16x8*)swzpc(sW2, row, row * 256 + ks * 64 + (h << 4));
        acc2[nt] = __builtin_amdgcn_mfma_f32_16x16x32_bf16(a2, b2, acc2[nt], 0, 0, 0);
      }
    }
    int gr[4];
#pragma unroll
    for (int j = 0; j < 4; ++j) gr[j] = sPerm[w * 16 + (h << 2) + j];
#pragma unroll
    for (int nt = 0; nt < 8; ++nt) {
#pragma unroll
      for (int j = 0; j < 4; ++j) {
        attr_out[(long long)gr[j] * 128 + nt * 16 + l15] = acc2[nt][j];
      }
    }
  }
}

extern "C" void kernel_launch(void* const* d_in, const int* in_sizes, int n_in,
                              void* d_out, int out_size, void* d_ws, size_t ws_size,
                              hipStream_t stream) {
  const float* x     = (const float*)d_in[0];
  const void*  ei    = d_in[1];
  const float* eattr = (const float*)d_in[2];
  const float* We    = (const float*)d_in[3];
  const float* Whu   = (const float*)d_in[4];
  const float* Whw   = (const float*)d_in[5];
  const float* W2    = (const float*)d_in[6];
  const float* Wemb  = (const float*)d_in[7];
  const float* Wattr = (const float*)d_in[8];

  float* out_emb  = (float*)d_out;
  float* out_attr = out_emb + (size_t)NN * 128;

  char* ws = (char*)d_ws;
  float*  sums = (float*)ws;                       // 25,600,000
  int*    cnt  = (int*)(ws + 25600000);            //    200,064
  int*    fill = (int*)(ws + 25800064);            //    200,064
  int*    offs = (int*)(ws + 26000128);            //    200,064
  int*    part = (int*)(ws + 26200192);            //      1,024
  int*    flag = (int*)(ws + 26201216);            //         64
  int*    perm = (int*)(ws + 26201280);            //  6,400,000
  __bf16* hu   = (__bf16*)(ws + 32601280);         // 12,800,000
  __bf16* hw   = (__bf16*)(ws + 45401280);         // 12,800,000
  __bf16* wHUW = (__bf16*)(ws + 58201280);         //    131,072
  __bf16* wET2 = wHUW + 65536;
  __bf16* wE   = wET2 + 65536;
  __bf16* wA   = wE + 16384;

  hipMemsetAsync(ws, 0, 26000128, stream);  // sums + cnt + fill
  detect_idx64<<<1, 1024, 0, stream>>>((const int*)ei, flag);
  prep_weights<<<640, 256, 0, stream>>>(We, Whu, Whw, W2, Wemb, Wattr, wHUW, wET2, wE, wA);
  k_hist<<<6250, 256, 0, stream>>>(ei, flag, cnt);
  k_part<<<196, 256, 0, stream>>>(cnt, part);
  k_scanpart<<<1, 256, 0, stream>>>(part, 196);
  k_offsets<<<196, 256, 0, stream>>>(cnt, part, offs);
  k_scatter<<<6250, 256, 0, stream>>>(ei, flag, offs, fill, perm);
  node_gemm<0><<<391, 512, 0, stream>>>(x, wHUW, hu, hw, nullptr, nullptr, nullptr);
  edge_fused<<<2048, 1024, 0, stream>>>(eattr, ei, flag, perm, wE, wA, hu, hw, sums, out_attr);
  node_gemm<1><<<391, 512, 0, stream>>>(x, wET2, nullptr, nullptr, sums, cnt, out_emb);
}